// Round 4
// baseline (309.038 us; speedup 1.0000x reference)
//
#include <hip/hip_runtime.h>

// DetectionCriterion: B=2e6, A=3, NC=3.
// output: (B,A,7) fp32, target: (B,A,5) fp32 -> scalar fp32 loss.
// loss = 2*BCE(output[:,:,4:], onehot(cls)) + 4*SSE(coords) + BCE(output[:,:,0], obj==1)
//
// Facts exploited:
//  - inputs in (1e-4, 1-1e-4): reference's max(log,-100) clamps never fire; logs safe.
//  - binary targets: each BCE term selects one of {p, 1-p} as a likelihood factor.
//  - per row: 2*cls_bce + obj_bce = -ln( (f0*f1*f2)^2 * fobj ), arg >= 1e-28 (no
//    underflow, > FLT_MIN) -> ONE hardware v_log_f32 per row.
//  - rows are 28/20 bytes: per-lane strided loads touch 64 lines/instr. Fix: stage
//    a 64-row quantum per wave via coalesced global_load_lds dword loads (linear
//    LDS layout = the DMA's required lane*4 order), then lane i consumes row i.
//    LDS read stride 7 (resp 5) words: gcd(7,32)=gcd(5,32)=1 -> <=2-way aliasing (free).

#define NROWS   6000000            // B*A
#define NQUANTA (NROWS / 64)       // 93750 quanta of 64 rows, exact
#define GRID    2048
#define BLOCK   256
#define NWAVES  (GRID * (BLOCK / 64))
#define LN2     0.69314718055994530942

#define GLOAD_LDS(g, l) __builtin_amdgcn_global_load_lds(                     \
    (const __attribute__((address_space(1))) unsigned int*)(g),               \
    (__attribute__((address_space(3))) unsigned int*)(l), 4, 0, 0)

__global__ __launch_bounds__(256) void det_loss_kernel(
        const float* __restrict__ out,
        const float* __restrict__ tgt,
        double* __restrict__ partial) {
    __shared__ float lds_out[4][448];   // 7 floats * 64 rows per wave
    __shared__ float lds_tgt[4][320];   // 5 floats * 64 rows per wave

    const int lane  = threadIdx.x & 63;
    const int wid   = threadIdx.x >> 6;
    const int gwave = blockIdx.x * 4 + wid;

    float* lo = lds_out[wid];
    float* lt = lds_tgt[wid];

    float xywh_sum = 0.0f;
    float log2_sum = 0.0f;

    for (int q = gwave; q < NQUANTA; q += NWAVES) {
        // make sure last iteration's ds_reads have retired before DMA overwrites
        asm volatile("s_waitcnt lgkmcnt(0)" ::: "memory");
        const float* po = out + (size_t)q * 448 + lane;  // dword per lane, coalesced
        const float* pt = tgt + (size_t)q * 320 + lane;
        #pragma unroll
        for (int k = 0; k < 7; ++k)
            GLOAD_LDS(po + k * 64, lo + k * 64);
        #pragma unroll
        for (int k = 0; k < 5; ++k)
            GLOAD_LDS(pt + k * 64, lt + k * 64);
        asm volatile("s_waitcnt vmcnt(0)" ::: "memory");

        // lane processes row = lane of this quantum
        const int b7 = lane * 7;
        const int b5 = lane * 5;
        float o0 = lo[b7 + 0], o1 = lo[b7 + 1], o2 = lo[b7 + 2], o3 = lo[b7 + 3];
        float o4 = lo[b7 + 4], o5 = lo[b7 + 5], o6 = lo[b7 + 6];
        float t0 = lt[b5 + 0], t1 = lt[b5 + 1], t2 = lt[b5 + 2], t3 = lt[b5 + 3];
        float t4 = lt[b5 + 4];

        float dx = o1 - t1, dy = o2 - t2, dz = o3 - t3;
        xywh_sum += dx * dx + dy * dy + dz * dz;

        int ci = (int)t4;
        float f0 = (ci == 0) ? o4 : 1.0f - o4;
        float f1 = (ci == 1) ? o5 : 1.0f - o5;
        float f2 = (ci == 2) ? o6 : 1.0f - o6;
        float fo = (t0 == 1.0f) ? o0 : 1.0f - o0;
        float m  = f0 * f1 * f2;       // >= 1e-12
        float v  = m * m * fo;         // >= 1e-28, safely > FLT_MIN
        log2_sum += __log2f(v);
    }

    // per-thread: loss contribution = 4*xywh_sum - ln2 * log2_sum
    double val = 4.0 * (double)xywh_sum - LN2 * (double)log2_sum;
    #pragma unroll
    for (int off = 32; off > 0; off >>= 1)
        val += __shfl_down(val, off, 64);

    __shared__ double wsum[4];
    if (lane == 0) wsum[wid] = val;
    __syncthreads();
    if (threadIdx.x == 0)
        partial[blockIdx.x] = wsum[0] + wsum[1] + wsum[2] + wsum[3];
}

__global__ __launch_bounds__(256) void final_reduce(
        const double* __restrict__ partial, float* __restrict__ outp) {
    double s = 0.0;
    for (int i = threadIdx.x; i < GRID; i += BLOCK) s += partial[i];
    #pragma unroll
    for (int off = 32; off > 0; off >>= 1)
        s += __shfl_down(s, off, 64);
    __shared__ double wsum[4];
    const int lane = threadIdx.x & 63;
    const int wid  = threadIdx.x >> 6;
    if (lane == 0) wsum[wid] = s;
    __syncthreads();
    if (threadIdx.x == 0)
        outp[0] = (float)(wsum[0] + wsum[1] + wsum[2] + wsum[3]);
}

extern "C" void kernel_launch(void* const* d_in, const int* in_sizes, int n_in,
                              void* d_out, int out_size, void* d_ws, size_t ws_size,
                              hipStream_t stream) {
    const float* out_p = (const float*)d_in[0];   // (B,A,7)
    const float* tgt_p = (const float*)d_in[1];   // (B,A,5)
    float* res = (float*)d_out;
    double* ws = (double*)d_ws;                   // 2048 doubles, all overwritten

    det_loss_kernel<<<GRID, BLOCK, 0, stream>>>(out_p, tgt_p, ws);
    final_reduce<<<1, BLOCK, 0, stream>>>(ws, res);
}

// Round 5
// 306.646 us; speedup vs baseline: 1.0078x; 1.0078x over previous
//
#include <hip/hip_runtime.h>

// DetectionCriterion: B=2e6, A=3, NC=3. 288 MB read -> scalar loss.
// Per row: loss = 4*|o[1:4]-t[1:4]|^2 - ln2 * log2( (f0*f1*f2)^2 * fobj )
// where fi = p or 1-p per binary/one-hot targets; arg >= 1e-28 (no clamp fires,
// inputs in (1e-4, 1-1e-4)) -> one v_log_f32 per row.
//
// R4 lesson: width-4 global_load_lds + vmcnt(0)-per-iter = request/drain bound
// (106 us, VALUBusy 8%). This version: 256-row quanta staged with width-16 DMA
// (7+5 dwordx4 chunks, exact), double-buffered with counted s_waitcnt vmcnt(12)
// so 12 loads stay in flight under compute (T3/T4). 1-wave blocks, private LDS,
// no barriers. Tail (6e6 mod 256 = 128 rows) via scalar loads in block 0.

#define NROWS     6000000
#define QROWS     256
#define NQ        (NROWS / QROWS)          // 23437 full quanta
#define TAILSTART (NQ * QROWS)             // 5999872
#define GRID      1536                     // 1 wave per block, 6 blocks/CU (24 KB LDS)
#define BLOCK     64
#define LN2       0.69314718055994530942

#define GL16(g, l) __builtin_amdgcn_global_load_lds(                          \
    (const __attribute__((address_space(1))) unsigned int*)(g),               \
    (__attribute__((address_space(3))) unsigned int*)(l), 16, 0, 0)

__device__ __forceinline__ float row_terms(
        const float* o, const float* t, float* xywh) {
    float dx = o[1] - t[1], dy = o[2] - t[2], dz = o[3] - t[3];
    *xywh += dx * dx + dy * dy + dz * dz;
    int ci = (int)t[4];
    float f0 = (ci == 0) ? o[4] : 1.0f - o[4];
    float f1 = (ci == 1) ? o[5] : 1.0f - o[5];
    float f2 = (ci == 2) ? o[6] : 1.0f - o[6];
    float fo = (t[0] == 1.0f) ? o[0] : 1.0f - o[0];
    float m = f0 * f1 * f2;                 // >= 1e-12
    return __log2f(m * m * fo);             // arg >= 1e-28 > FLT_MIN
}

__global__ __launch_bounds__(64) void det_loss_kernel(
        const float* __restrict__ outp,
        const float* __restrict__ tgtp,
        double* __restrict__ partial) {
    __shared__ float lds[2][3072];          // 2 x 12288 B (7168 out + 5120 tgt)
    const int lane = threadIdx.x;
    const int w = blockIdx.x;

    // quanta for this wave: q = w, w+GRID, ...
    const int nmine = (NQ - 1 - w) / GRID + 1;   // w < GRID <= NQ always

    // prologue: issue quantum 0 and 1
    {
        const float* so = outp + (size_t)w * (QROWS * 7);
        const float* st = tgtp + (size_t)w * (QROWS * 5);
        float* dst = &lds[0][0];
        #pragma unroll
        for (int c = 0; c < 7; ++c) GL16(so + c * 256 + lane * 4, dst + c * 256);
        #pragma unroll
        for (int c = 0; c < 5; ++c) GL16(st + c * 256 + lane * 4, dst + 1792 + c * 256);
    }
    if (nmine > 1) {
        const size_t q = (size_t)w + GRID;
        const float* so = outp + q * (QROWS * 7);
        const float* st = tgtp + q * (QROWS * 5);
        float* dst = &lds[1][0];
        #pragma unroll
        for (int c = 0; c < 7; ++c) GL16(so + c * 256 + lane * 4, dst + c * 256);
        #pragma unroll
        for (int c = 0; c < 5; ++c) GL16(st + c * 256 + lane * 4, dst + 1792 + c * 256);
    }

    double acc = 0.0;
    int cur = 0;
    for (int t = 0; t < nmine; ++t) {
        // wait for quantum t only: 12 loads of quantum t+1 may stay in flight
        if (t + 1 < nmine) { asm volatile("s_waitcnt vmcnt(12)" ::: "memory"); }
        else               { asm volatile("s_waitcnt vmcnt(0)"  ::: "memory"); }

        // lane's 4 rows: out at lane*112 B (7 x b128), tgt at lane*80 B (5 x b128)
        float of[28], tf[20];
        {
            const float* bo = &lds[cur][0] + lane * 28;
            #pragma unroll
            for (int k = 0; k < 7; ++k) {
                float4 v = *reinterpret_cast<const float4*>(bo + 4 * k);
                of[4*k+0] = v.x; of[4*k+1] = v.y; of[4*k+2] = v.z; of[4*k+3] = v.w;
            }
            const float* bt = &lds[cur][1792] + lane * 20;
            #pragma unroll
            for (int k = 0; k < 5; ++k) {
                float4 v = *reinterpret_cast<const float4*>(bt + 4 * k);
                tf[4*k+0] = v.x; tf[4*k+1] = v.y; tf[4*k+2] = v.z; tf[4*k+3] = v.w;
            }
        }
        // all ds_reads retired before the DMA below may overwrite this buffer
        asm volatile("s_waitcnt lgkmcnt(0)" ::: "memory");
        __builtin_amdgcn_sched_barrier(0);

        if (t + 2 < nmine) {   // refill the buffer we just consumed
            const size_t q = (size_t)w + (size_t)(t + 2) * GRID;
            const float* so = outp + q * (QROWS * 7);
            const float* st = tgtp + q * (QROWS * 5);
            float* dst = &lds[cur][0];
            #pragma unroll
            for (int c = 0; c < 7; ++c) GL16(so + c * 256 + lane * 4, dst + c * 256);
            #pragma unroll
            for (int c = 0; c < 5; ++c) GL16(st + c * 256 + lane * 4, dst + 1792 + c * 256);
        }

        float xy = 0.0f, lg = 0.0f;
        #pragma unroll
        for (int r = 0; r < 4; ++r)
            lg += row_terms(of + 7 * r, tf + 5 * r, &xy);
        acc += 4.0 * (double)xy - LN2 * (double)lg;
        cur ^= 1;
    }

    // tail: 128 rows, block 0 only, scalar loads (negligible volume)
    if (w == 0) {
        int r = TAILSTART + lane * 2;
        #pragma unroll
        for (int rr = 0; rr < 2; ++rr) {
            const float* o = outp + (size_t)(r + rr) * 7;
            const float* t = tgtp + (size_t)(r + rr) * 5;
            float ob[7], tb[5];
            #pragma unroll
            for (int j = 0; j < 7; ++j) ob[j] = o[j];
            #pragma unroll
            for (int j = 0; j < 5; ++j) tb[j] = t[j];
            float xy = 0.0f;
            float lg = row_terms(ob, tb, &xy);
            acc += 4.0 * (double)xy - LN2 * (double)lg;
        }
    }

    // wave64 reduce (block == 1 wave)
    #pragma unroll
    for (int off = 32; off > 0; off >>= 1)
        acc += __shfl_down(acc, off, 64);
    if (lane == 0) partial[w] = acc;
}

__global__ __launch_bounds__(256) void final_reduce(
        const double* __restrict__ partial, float* __restrict__ outp) {
    double s = 0.0;
    for (int i = threadIdx.x; i < GRID; i += 256) s += partial[i];
    #pragma unroll
    for (int off = 32; off > 0; off >>= 1)
        s += __shfl_down(s, off, 64);
    __shared__ double wsum[4];
    const int lane = threadIdx.x & 63;
    const int wid  = threadIdx.x >> 6;
    if (lane == 0) wsum[wid] = s;
    __syncthreads();
    if (threadIdx.x == 0)
        outp[0] = (float)(wsum[0] + wsum[1] + wsum[2] + wsum[3]);
}

extern "C" void kernel_launch(void* const* d_in, const int* in_sizes, int n_in,
                              void* d_out, int out_size, void* d_ws, size_t ws_size,
                              hipStream_t stream) {
    const float* out_p = (const float*)d_in[0];   // (B,A,7)
    const float* tgt_p = (const float*)d_in[1];   // (B,A,5)
    float* res = (float*)d_out;
    double* ws = (double*)d_ws;                   // GRID doubles, all overwritten

    det_loss_kernel<<<GRID, BLOCK, 0, stream>>>(out_p, tgt_p, ws);
    final_reduce<<<1, 256, 0, stream>>>(ws, res);
}